// Round 1
// baseline (239.552 us; speedup 1.0000x reference)
//
#include <hip/hip_runtime.h>
#include <hip/hip_bf16.h>

// Problem constants
#define BB 2
#define HH 56
#define WW 56
#define CC 256
#define HEADS 8
#define HD 32
#define KW 7
#define NPIX (BB*HH*WW)           // 6272
#define KV_N 512

// ---------------- GEMM: C[M][N] = A[M][K] @ Wt[N][K]^T + bias[N] ----------------
// BM=BN=64, BK=16, 256 threads, 4x4 per thread.
__global__ __launch_bounds__(256) void gemm_nt_bias(
    const float* __restrict__ A, const float* __restrict__ Wt,
    const float* __restrict__ bias, float* __restrict__ C,
    int M, int N, int Kd)
{
    __shared__ float As[16][65];
    __shared__ float Bs[16][65];
    const int tid = threadIdx.x;
    const int bm = blockIdx.y * 64;
    const int bn = blockIdx.x * 64;
    const int tx = tid & 15, ty = tid >> 4;
    const int lr = tid >> 2;          // 0..63 (row within tile)
    const int lc = (tid & 3) << 2;    // 0,4,8,12 (k within BK)

    const float* Ag = A  + (size_t)(bm + lr) * Kd + lc;
    const float* Bg = Wt + (size_t)(bn + lr) * Kd + lc;

    float acc[4][4] = {};

    for (int k0 = 0; k0 < Kd; k0 += 16) {
        float4 av = *(const float4*)(Ag + k0);
        float4 bv = *(const float4*)(Bg + k0);
        __syncthreads();
        As[lc+0][lr] = av.x; As[lc+1][lr] = av.y; As[lc+2][lr] = av.z; As[lc+3][lr] = av.w;
        Bs[lc+0][lr] = bv.x; Bs[lc+1][lr] = bv.y; Bs[lc+2][lr] = bv.z; Bs[lc+3][lr] = bv.w;
        __syncthreads();
        #pragma unroll
        for (int kk = 0; kk < 16; ++kk) {
            float a0 = As[kk][ty*4+0], a1 = As[kk][ty*4+1];
            float a2 = As[kk][ty*4+2], a3 = As[kk][ty*4+3];
            float b0 = Bs[kk][tx*4+0], b1 = Bs[kk][tx*4+1];
            float b2 = Bs[kk][tx*4+2], b3 = Bs[kk][tx*4+3];
            acc[0][0] += a0*b0; acc[0][1] += a0*b1; acc[0][2] += a0*b2; acc[0][3] += a0*b3;
            acc[1][0] += a1*b0; acc[1][1] += a1*b1; acc[1][2] += a1*b2; acc[1][3] += a1*b3;
            acc[2][0] += a2*b0; acc[2][1] += a2*b1; acc[2][2] += a2*b2; acc[2][3] += a2*b3;
            acc[3][0] += a3*b0; acc[3][1] += a3*b1; acc[3][2] += a3*b2; acc[3][3] += a3*b3;
        }
    }
    #pragma unroll
    for (int i = 0; i < 4; ++i) {
        #pragma unroll
        for (int j = 0; j < 4; ++j) {
            int n = bn + tx*4 + j;
            C[(size_t)(bm + ty*4 + i) * N + n] = acc[i][j] + bias[n];
        }
    }
}

// ---------------- Neighborhood attention ----------------
// One thread per (pixel, head). kv layout: [pix][512] where c = t*256 + head*32 + d.
__global__ __launch_bounds__(256) void natt_kernel(
    const float* __restrict__ q_extra, const float* __restrict__ kv,
    const float* __restrict__ rpb, float* __restrict__ attn_out)
{
    const int gid = blockIdx.x * 256 + threadIdx.x;   // 0..50175
    const int head = gid & 7;
    const int pix  = gid >> 3;
    const int j = pix % WW;
    const int i = (pix / WW) % HH;
    const int b = pix / (WW * HH);

    const float scale = 0.17677669529663687f;  // 32^-0.5

    float q[HD];
    const float* qp = q_extra + (size_t)pix * CC + head * HD;
    #pragma unroll
    for (int d = 0; d < HD; d += 4) {
        float4 v = *(const float4*)(qp + d);
        q[d+0] = v.x * scale; q[d+1] = v.y * scale;
        q[d+2] = v.z * scale; q[d+3] = v.w * scale;
    }

    const int sh = min(max(i - 3, 0), HH - KW);   // window start row
    const int sw = min(max(j - 3, 0), WW - KW);   // window start col
    const int pbi0 = sh - i + 6;                  // bias row base
    const int pbj0 = sw - j + 6;                  // bias col base

    float s[KW*KW];
    float mmax = -3.4e38f;
    #pragma unroll
    for (int a = 0; a < KW; ++a) {
        const float* kp = kv + ((size_t)((b*HH + sh + a) * WW + sw)) * KV_N + head * HD;
        const float* bp = rpb + (size_t)(head * 13 + (pbi0 + a)) * 13 + pbj0;
        #pragma unroll
        for (int c = 0; c < KW; ++c) {
            float dot = 0.f;
            #pragma unroll
            for (int d = 0; d < HD; d += 4) {
                float4 kvv = *(const float4*)(kp + c*KV_N + d);
                dot += q[d+0]*kvv.x + q[d+1]*kvv.y + q[d+2]*kvv.z + q[d+3]*kvv.w;
            }
            float sc = dot + bp[c];
            s[a*KW+c] = sc;
            mmax = fmaxf(mmax, sc);
        }
    }
    float sum = 0.f;
    #pragma unroll
    for (int t = 0; t < KW*KW; ++t) {
        s[t] = __expf(s[t] - mmax);
        sum += s[t];
    }
    const float inv = 1.0f / sum;

    float acc[HD] = {};
    #pragma unroll
    for (int a = 0; a < KW; ++a) {
        const float* vp = kv + ((size_t)((b*HH + sh + a) * WW + sw)) * KV_N + CC + head * HD;
        #pragma unroll
        for (int c = 0; c < KW; ++c) {
            float p = s[a*KW+c];
            #pragma unroll
            for (int d = 0; d < HD; d += 4) {
                float4 vv = *(const float4*)(vp + c*KV_N + d);
                acc[d+0] += p*vv.x; acc[d+1] += p*vv.y;
                acc[d+2] += p*vv.z; acc[d+3] += p*vv.w;
            }
        }
    }
    float* op = attn_out + (size_t)pix * CC + head * HD;
    #pragma unroll
    for (int d = 0; d < HD; d += 4) {
        float4 o;
        o.x = acc[d+0]*inv; o.y = acc[d+1]*inv;
        o.z = acc[d+2]*inv; o.w = acc[d+3]*inv;
        *(float4*)(op + d) = o;
    }
}

extern "C" void kernel_launch(void* const* d_in, const int* in_sizes, int n_in,
                              void* d_out, int out_size, void* d_ws, size_t ws_size,
                              hipStream_t stream) {
    const float* x       = (const float*)d_in[0];
    const float* q_extra = (const float*)d_in[1];
    const float* kv_w    = (const float*)d_in[2];
    const float* kv_b    = (const float*)d_in[3];
    const float* rpb     = (const float*)d_in[4];
    const float* proj_w  = (const float*)d_in[5];
    const float* proj_b  = (const float*)d_in[6];
    float* out = (float*)d_out;

    float* kv       = (float*)d_ws;                      // NPIX * 512 floats
    float* attn_out = kv + (size_t)NPIX * KV_N;          // NPIX * 256 floats

    // 1) kv = x @ kv_w^T + kv_b   (M=6272, N=512, K=256)
    {
        dim3 grid(KV_N/64, NPIX/64);
        gemm_nt_bias<<<grid, 256, 0, stream>>>(x, kv_w, kv_b, kv, NPIX, KV_N, CC);
    }
    // 2) neighborhood attention
    {
        dim3 grid((NPIX*HEADS)/256);
        natt_kernel<<<grid, 256, 0, stream>>>(q_extra, kv, rpb, attn_out);
    }
    // 3) out = attn_out @ proj_w^T + proj_b   (M=6272, N=256, K=256)
    {
        dim3 grid(CC/64, NPIX/64);
        gemm_nt_bias<<<grid, 256, 0, stream>>>(attn_out, proj_w, proj_b, out, NPIX, CC, CC);
    }
}

// Round 2
// 155.391 us; speedup vs baseline: 1.5416x; 1.5416x over previous
//
#include <hip/hip_runtime.h>
#include <hip/hip_bf16.h>

// Problem constants
#define BB 2
#define HH 56
#define WW 56
#define CC 256
#define HEADS 8
#define HD 32
#define KW 7
#define NPIX (BB*HH*WW)           // 6272
#define KV_N 512

// ---------------- GEMM: C[M][N] = A[M][K] @ Wt[N][K]^T + bias[N] ----------------
// BN=64, BK=16, 256 threads. BM=128 -> 8x4 per thread; BM=64 -> 4x4.
template<int BM>
__global__ __launch_bounds__(256) void gemm_nt_bias(
    const float* __restrict__ A, const float* __restrict__ Wt,
    const float* __restrict__ bias, float* __restrict__ C,
    int M, int N, int Kd)
{
    constexpr int BN = 64, BK = 16;
    constexpr int TM = BM / 16;                 // rows per thread (8 or 4)
    __shared__ float As[BK][BM + 4];            // row stride keeps 16B alignment
    __shared__ float Bs[BK][BN + 4];

    const int tid = threadIdx.x;
    const int bm = blockIdx.y * BM;
    const int bn = blockIdx.x * BN;
    const int tx = tid & 15, ty = tid >> 4;

    const int sr  = tid >> 2;                   // 0..63 staging row
    const int akq = (tid & 3) * 4;              // k offset 0,4,8,12

    const float* Bg = Wt + (size_t)(bn + sr) * Kd + akq;

    float acc[TM][4] = {};

    for (int k0 = 0; k0 < Kd; k0 += BK) {
        float4 av[BM / 64];
        #pragma unroll
        for (int it = 0; it < BM / 64; ++it)
            av[it] = *(const float4*)(A + (size_t)(bm + sr + it*64) * Kd + akq + k0);
        float4 bv = *(const float4*)(Bg + k0);

        __syncthreads();
        #pragma unroll
        for (int it = 0; it < BM / 64; ++it) {
            As[akq+0][sr + it*64] = av[it].x;
            As[akq+1][sr + it*64] = av[it].y;
            As[akq+2][sr + it*64] = av[it].z;
            As[akq+3][sr + it*64] = av[it].w;
        }
        Bs[akq+0][sr] = bv.x; Bs[akq+1][sr] = bv.y;
        Bs[akq+2][sr] = bv.z; Bs[akq+3][sr] = bv.w;
        __syncthreads();

        #pragma unroll
        for (int kk = 0; kk < BK; ++kk) {
            float a[TM], bb[4];
            #pragma unroll
            for (int i = 0; i < TM; ++i) a[i] = As[kk][ty*TM + i];
            #pragma unroll
            for (int j = 0; j < 4; ++j) bb[j] = Bs[kk][tx*4 + j];
            #pragma unroll
            for (int i = 0; i < TM; ++i)
                #pragma unroll
                for (int j = 0; j < 4; ++j)
                    acc[i][j] += a[i] * bb[j];
        }
    }

    const float4 bvv = *(const float4*)(bias + bn + tx*4);
    #pragma unroll
    for (int i = 0; i < TM; ++i) {
        float4 o;
        o.x = acc[i][0] + bvv.x; o.y = acc[i][1] + bvv.y;
        o.z = acc[i][2] + bvv.z; o.w = acc[i][3] + bvv.w;
        *(float4*)(&C[(size_t)(bm + ty*TM + i) * N + bn + tx*4]) = o;
    }
}

// ---------------- Neighborhood attention ----------------
// 4 lanes per (pixel, head); lane `sub` owns dims [sub*8, sub*8+8).
// kv layout: [pix][512] where c = t*256 + head*32 + d.
__global__ __launch_bounds__(256) void natt_kernel(
    const float* __restrict__ q_extra, const float* __restrict__ kv,
    const float* __restrict__ rpb, float* __restrict__ attn_out)
{
    const int gid  = blockIdx.x * 256 + threadIdx.x;   // 0..200703
    const int sub  = gid & 3;
    const int ph   = gid >> 2;        // (pixel, head)
    const int head = ph & 7;
    const int pix  = ph >> 3;
    const int j = pix % WW;
    const int i = (pix / WW) % HH;
    const int b = pix / (WW * HH);

    const float scale = 0.17677669529663687f;  // 32^-0.5
    const int d0 = sub * 8;

    float q[8];
    {
        const float* qp = q_extra + (size_t)pix * CC + head * HD + d0;
        float4 v0 = *(const float4*)(qp);
        float4 v1 = *(const float4*)(qp + 4);
        q[0] = v0.x*scale; q[1] = v0.y*scale; q[2] = v0.z*scale; q[3] = v0.w*scale;
        q[4] = v1.x*scale; q[5] = v1.y*scale; q[6] = v1.z*scale; q[7] = v1.w*scale;
    }

    const int sh = min(max(i - 3, 0), HH - KW);
    const int sw = min(max(j - 3, 0), WW - KW);
    const int pbi0 = sh - i + 6;
    const int pbj0 = sw - j + 6;

    // partial dots over this lane's 8 dims
    float s[KW*KW];
    #pragma unroll
    for (int a = 0; a < KW; ++a) {
        const float* kp = kv + ((size_t)((b*HH + sh + a) * WW + sw)) * KV_N + head * HD + d0;
        #pragma unroll
        for (int c = 0; c < KW; ++c) {
            float4 k0v = *(const float4*)(kp + c*KV_N);
            float4 k1v = *(const float4*)(kp + c*KV_N + 4);
            s[a*KW+c] = q[0]*k0v.x + q[1]*k0v.y + q[2]*k0v.z + q[3]*k0v.w
                      + q[4]*k1v.x + q[5]*k1v.y + q[6]*k1v.z + q[7]*k1v.w;
        }
    }

    // quad reduce, add bias, track max
    float mmax = -3.4e38f;
    #pragma unroll
    for (int a = 0; a < KW; ++a) {
        const float* bp = rpb + (size_t)(head * 13 + (pbi0 + a)) * 13 + pbj0;
        #pragma unroll
        for (int c = 0; c < KW; ++c) {
            float v = s[a*KW+c];
            v += __shfl_xor(v, 1);
            v += __shfl_xor(v, 2);
            v += bp[c];
            s[a*KW+c] = v;
            mmax = fmaxf(mmax, v);
        }
    }

    float sum = 0.f;
    #pragma unroll
    for (int t = 0; t < KW*KW; ++t) {
        s[t] = __expf(s[t] - mmax);
        sum += s[t];
    }
    const float inv = 1.0f / sum;

    // PV over this lane's 8 dims
    float acc[8] = {};
    #pragma unroll
    for (int a = 0; a < KW; ++a) {
        const float* vp = kv + ((size_t)((b*HH + sh + a) * WW + sw)) * KV_N + CC + head * HD + d0;
        #pragma unroll
        for (int c = 0; c < KW; ++c) {
            float p = s[a*KW+c];
            float4 v0 = *(const float4*)(vp + c*KV_N);
            float4 v1 = *(const float4*)(vp + c*KV_N + 4);
            acc[0] += p*v0.x; acc[1] += p*v0.y; acc[2] += p*v0.z; acc[3] += p*v0.w;
            acc[4] += p*v1.x; acc[5] += p*v1.y; acc[6] += p*v1.z; acc[7] += p*v1.w;
        }
    }

    float* op = attn_out + (size_t)pix * CC + head * HD + d0;
    float4 o0, o1;
    o0.x = acc[0]*inv; o0.y = acc[1]*inv; o0.z = acc[2]*inv; o0.w = acc[3]*inv;
    o1.x = acc[4]*inv; o1.y = acc[5]*inv; o1.z = acc[6]*inv; o1.w = acc[7]*inv;
    *(float4*)(op)     = o0;
    *(float4*)(op + 4) = o1;
}

extern "C" void kernel_launch(void* const* d_in, const int* in_sizes, int n_in,
                              void* d_out, int out_size, void* d_ws, size_t ws_size,
                              hipStream_t stream) {
    const float* x       = (const float*)d_in[0];
    const float* q_extra = (const float*)d_in[1];
    const float* kv_w    = (const float*)d_in[2];
    const float* kv_b    = (const float*)d_in[3];
    const float* rpb     = (const float*)d_in[4];
    const float* proj_w  = (const float*)d_in[5];
    const float* proj_b  = (const float*)d_in[6];
    float* out = (float*)d_out;

    float* kv       = (float*)d_ws;                      // NPIX * 512 floats
    float* attn_out = kv + (size_t)NPIX * KV_N;          // NPIX * 256 floats

    // 1) kv = x @ kv_w^T + kv_b   (M=6272, N=512, K=256), BM=128
    {
        dim3 grid(KV_N/64, NPIX/128);
        gemm_nt_bias<128><<<grid, 256, 0, stream>>>(x, kv_w, kv_b, kv, NPIX, KV_N, CC);
    }
    // 2) neighborhood attention (4 lanes per (pixel,head))
    {
        dim3 grid((NPIX*HEADS*4)/256);
        natt_kernel<<<grid, 256, 0, stream>>>(q_extra, kv, rpb, attn_out);
    }
    // 3) out = attn_out @ proj_w^T + proj_b   (M=6272, N=256, K=256), BM=64
    {
        dim3 grid(CC/64, NPIX/64);
        gemm_nt_bias<64><<<grid, 256, 0, stream>>>(attn_out, proj_w, proj_b, out, NPIX, CC, CC);
    }
}

// Round 3
// 126.472 us; speedup vs baseline: 1.8941x; 1.2287x over previous
//
#include <hip/hip_runtime.h>
#include <hip/hip_bf16.h>

// Problem constants
#define BB 2
#define HH 56
#define WW 56
#define CC 256
#define HEADS 8
#define HD 32
#define KW 7
#define NPIX (BB*HH*WW)           // 6272
#define KV_N 512

using bf16x8 = __attribute__((ext_vector_type(8))) short;
using f32x4  = __attribute__((ext_vector_type(4))) float;

__device__ __forceinline__ ushort f2bf(float f) {
    union { float f; uint u; } v; v.f = f;
    uint r = v.u + 0x7FFF + ((v.u >> 16) & 1);   // round-to-nearest-even
    return (ushort)(r >> 16);
}

// ---------------- bf16 MFMA GEMM: C[M][N] = A[M][K] @ Wt[N][K]^T + bias[N] ----
// 256 threads = 4 waves in 2x2; wave tile (BM/2)x(BN/2); BK=64 chunks.
// LDS row stride 72 bf16 (144B = 36 banks -> 2-way conflict on b128 reads, free).
template<int BM, int BN>
__global__ __launch_bounds__(256) void gemm_bf16_nt(
    const float* __restrict__ A, const float* __restrict__ Wt,
    const float* __restrict__ bias, float* __restrict__ C,
    int M, int N, int Kd)
{
    constexpr int BK  = 64;
    constexpr int LDT = 72;                 // LDS row stride (bf16 elems)
    constexpr int WTM = BM / 2, WTN = BN / 2;
    constexpr int MF  = WTM / 16, NF = WTN / 16;

    __shared__ ushort As[BM][LDT];
    __shared__ ushort Bs[BN][LDT];

    const int tid  = threadIdx.x;
    const int lane = tid & 63;
    const int wid  = tid >> 6;
    const int wm   = wid >> 1;              // 0..1
    const int wn   = wid & 1;               // 0..1
    const int bm   = blockIdx.y * BM;
    const int bn   = blockIdx.x * BN;

    const int srow = tid >> 3;              // 0..31 staging row within pass
    const int skq  = (tid & 7) * 8;         // k offset 0..56

    f32x4 acc[MF][NF] = {};

    for (int k0 = 0; k0 < Kd; k0 += BK) {
        // stage A (BM x 64) f32 -> bf16
        #pragma unroll
        for (int p = 0; p < BM / 32; ++p) {
            const int r = p * 32 + srow;
            const float* src = A + (size_t)(bm + r) * Kd + k0 + skq;
            float4 f0 = *(const float4*)(src);
            float4 f1 = *(const float4*)(src + 4);
            bf16x8 v;
            v[0]=f2bf(f0.x); v[1]=f2bf(f0.y); v[2]=f2bf(f0.z); v[3]=f2bf(f0.w);
            v[4]=f2bf(f1.x); v[5]=f2bf(f1.y); v[6]=f2bf(f1.z); v[7]=f2bf(f1.w);
            *(bf16x8*)&As[r][skq] = v;
        }
        // stage B (BN x 64)
        #pragma unroll
        for (int p = 0; p < BN / 32; ++p) {
            const int r = p * 32 + srow;
            const float* src = Wt + (size_t)(bn + r) * Kd + k0 + skq;
            float4 f0 = *(const float4*)(src);
            float4 f1 = *(const float4*)(src + 4);
            bf16x8 v;
            v[0]=f2bf(f0.x); v[1]=f2bf(f0.y); v[2]=f2bf(f0.z); v[3]=f2bf(f0.w);
            v[4]=f2bf(f1.x); v[5]=f2bf(f1.y); v[6]=f2bf(f1.z); v[7]=f2bf(f1.w);
            *(bf16x8*)&Bs[r][skq] = v;
        }
        __syncthreads();

        #pragma unroll
        for (int ks = 0; ks < 2; ++ks) {
            const int koff = ks * 32 + (lane >> 4) * 8;
            bf16x8 af[MF], bf[NF];
            #pragma unroll
            for (int m = 0; m < MF; ++m)
                af[m] = *(const bf16x8*)&As[wm*WTM + m*16 + (lane & 15)][koff];
            #pragma unroll
            for (int n = 0; n < NF; ++n)
                bf[n] = *(const bf16x8*)&Bs[wn*WTN + n*16 + (lane & 15)][koff];
            #pragma unroll
            for (int m = 0; m < MF; ++m)
                #pragma unroll
                for (int n = 0; n < NF; ++n)
                    acc[m][n] = __builtin_amdgcn_mfma_f32_16x16x32_bf16(af[m], bf[n], acc[m][n], 0, 0, 0);
        }
        __syncthreads();
    }

    // epilogue: C row=(lane>>4)*4+r, col=lane&15 within each 16x16 frag
    #pragma unroll
    for (int n = 0; n < NF; ++n) {
        const int col = bn + wn*WTN + n*16 + (lane & 15);
        const float bval = bias[col];
        #pragma unroll
        for (int m = 0; m < MF; ++m) {
            const int row0 = bm + wm*WTM + m*16 + (lane >> 4) * 4;
            #pragma unroll
            for (int r = 0; r < 4; ++r)
                C[(size_t)(row0 + r) * N + col] = acc[m][n][r] + bval;
        }
    }
}

// ---------------- Neighborhood attention ----------------
// 4 lanes per (pixel, head); lane `sub` owns dims [sub*8, sub*8+8).
// kv layout: [pix][512] where c = t*256 + head*32 + d.
__global__ __launch_bounds__(256) void natt_kernel(
    const float* __restrict__ q_extra, const float* __restrict__ kv,
    const float* __restrict__ rpb, float* __restrict__ attn_out)
{
    const int gid  = blockIdx.x * 256 + threadIdx.x;   // 0..200703
    const int sub  = gid & 3;
    const int ph   = gid >> 2;        // (pixel, head)
    const int head = ph & 7;
    const int pix  = ph >> 3;
    const int j = pix % WW;
    const int i = (pix / WW) % HH;
    const int b = pix / (WW * HH);

    const float scale = 0.17677669529663687f;  // 32^-0.5
    const int d0 = sub * 8;

    float q[8];
    {
        const float* qp = q_extra + (size_t)pix * CC + head * HD + d0;
        float4 v0 = *(const float4*)(qp);
        float4 v1 = *(const float4*)(qp + 4);
        q[0] = v0.x*scale; q[1] = v0.y*scale; q[2] = v0.z*scale; q[3] = v0.w*scale;
        q[4] = v1.x*scale; q[5] = v1.y*scale; q[6] = v1.z*scale; q[7] = v1.w*scale;
    }

    const int sh = min(max(i - 3, 0), HH - KW);
    const int sw = min(max(j - 3, 0), WW - KW);
    const int pbi0 = sh - i + 6;
    const int pbj0 = sw - j + 6;

    float s[KW*KW];
    #pragma unroll
    for (int a = 0; a < KW; ++a) {
        const float* kp = kv + ((size_t)((b*HH + sh + a) * WW + sw)) * KV_N + head * HD + d0;
        #pragma unroll
        for (int c = 0; c < KW; ++c) {
            float4 k0v = *(const float4*)(kp + c*KV_N);
            float4 k1v = *(const float4*)(kp + c*KV_N + 4);
            s[a*KW+c] = q[0]*k0v.x + q[1]*k0v.y + q[2]*k0v.z + q[3]*k0v.w
                      + q[4]*k1v.x + q[5]*k1v.y + q[6]*k1v.z + q[7]*k1v.w;
        }
    }

    float mmax = -3.4e38f;
    #pragma unroll
    for (int a = 0; a < KW; ++a) {
        const float* bp = rpb + (size_t)(head * 13 + (pbi0 + a)) * 13 + pbj0;
        #pragma unroll
        for (int c = 0; c < KW; ++c) {
            float v = s[a*KW+c];
            v += __shfl_xor(v, 1);
            v += __shfl_xor(v, 2);
            v += bp[c];
            s[a*KW+c] = v;
            mmax = fmaxf(mmax, v);
        }
    }

    float sum = 0.f;
    #pragma unroll
    for (int t = 0; t < KW*KW; ++t) {
        s[t] = __expf(s[t] - mmax);
        sum += s[t];
    }
    const float inv = 1.0f / sum;

    float acc[8] = {};
    #pragma unroll
    for (int a = 0; a < KW; ++a) {
        const float* vp = kv + ((size_t)((b*HH + sh + a) * WW + sw)) * KV_N + CC + head * HD + d0;
        #pragma unroll
        for (int c = 0; c < KW; ++c) {
            float p = s[a*KW+c];
            float4 v0 = *(const float4*)(vp + c*KV_N);
            float4 v1 = *(const float4*)(vp + c*KV_N + 4);
            acc[0] += p*v0.x; acc[1] += p*v0.y; acc[2] += p*v0.z; acc[3] += p*v0.w;
            acc[4] += p*v1.x; acc[5] += p*v1.y; acc[6] += p*v1.z; acc[7] += p*v1.w;
        }
    }

    float* op = attn_out + (size_t)pix * CC + head * HD + d0;
    float4 o0, o1;
    o0.x = acc[0]*inv; o0.y = acc[1]*inv; o0.z = acc[2]*inv; o0.w = acc[3]*inv;
    o1.x = acc[4]*inv; o1.y = acc[5]*inv; o1.z = acc[6]*inv; o1.w = acc[7]*inv;
    *(float4*)(op)     = o0;
    *(float4*)(op + 4) = o1;
}

extern "C" void kernel_launch(void* const* d_in, const int* in_sizes, int n_in,
                              void* d_out, int out_size, void* d_ws, size_t ws_size,
                              hipStream_t stream) {
    const float* x       = (const float*)d_in[0];
    const float* q_extra = (const float*)d_in[1];
    const float* kv_w    = (const float*)d_in[2];
    const float* kv_b    = (const float*)d_in[3];
    const float* rpb     = (const float*)d_in[4];
    const float* proj_w  = (const float*)d_in[5];
    const float* proj_b  = (const float*)d_in[6];
    float* out = (float*)d_out;

    float* kv       = (float*)d_ws;                      // NPIX * 512 floats
    float* attn_out = kv + (size_t)NPIX * KV_N;          // NPIX * 256 floats

    // 1) kv = x @ kv_w^T + kv_b   (M=6272, N=512, K=256), MFMA bf16
    {
        dim3 grid(KV_N/64, NPIX/128);
        gemm_bf16_nt<128,64><<<grid, 256, 0, stream>>>(x, kv_w, kv_b, kv, NPIX, KV_N, CC);
    }
    // 2) neighborhood attention (4 lanes per (pixel,head))
    {
        dim3 grid((NPIX*HEADS*4)/256);
        natt_kernel<<<grid, 256, 0, stream>>>(q_extra, kv, rpb, attn_out);
    }
    // 3) out = attn_out @ proj_w^T + proj_b   (M=6272, N=256, K=256), MFMA bf16
    {
        dim3 grid(CC/64, NPIX/64);
        gemm_bf16_nt<64,64><<<grid, 256, 0, stream>>>(attn_out, proj_w, proj_b, out, NPIX, CC, CC);
    }
}